// Round 1
// baseline (1371.493 us; speedup 1.0000x reference)
//
#include <hip/hip_runtime.h>
#include <hip/hip_bf16.h>

constexpr int FDIM  = 128;
constexpr int BSH   = 5;      // 32 nodes per bucket
constexpr int BWD   = 32;
constexpr int NBMAX = 2048;   // supports N <= 65536 (N = 50000)

typedef __attribute__((ext_vector_type(8))) short bf16x8;   // 8 bf16 = 4 VGPRs
typedef __attribute__((ext_vector_type(4))) float f32x4;
typedef __attribute__((ext_vector_type(2))) float f32x2;

static __device__ __forceinline__ ushort f2bf(float f){
    union { float f; unsigned u; } v; v.f = f;
    unsigned r = v.u + 0x7fffu + ((v.u >> 16) & 1u);   // RNE
    return (ushort)(r >> 16);
}
static __device__ __forceinline__ unsigned char f2fp8(float f){
    return (unsigned char)(__builtin_amdgcn_cvt_pk_fp8_f32(f, f, 0, false) & 0xff);
}

// ---------------- pass 1 (fused): per-block bucket histogram | x cast | weight swizzle ----------------
// Bucket histogram replaces the old per-edge global atomic degree/rank pass: dst is read ONCE,
// all counting is in LDS, output is a dense [SB][NB] count matrix. Zero global atomics.

__global__ __launch_bounds__(256) void k_pass1(
    const int* __restrict__ dst, int* __restrict__ hist,
    int E, int ESB, int NB, int SB,
    const float* __restrict__ xsrc, ushort* __restrict__ xb, unsigned char* __restrict__ x8, int nx, int gC,
    const float* __restrict__ W1_l, const float* __restrict__ W1_r,
    const float* __restrict__ Wl1,
    const float* __restrict__ W2_l, const float* __restrict__ W2_r,
    ushort* __restrict__ Wf1, ushort* __restrict__ Wfm, ushort* __restrict__ Wf2)
{
    const int b = (int)blockIdx.x;
    if (b < SB){
        __shared__ int lh[NBMAX];
        for (int i = (int)threadIdx.x; i < NB; i += 256) lh[i] = 0;
        __syncthreads();
        const int e1 = min(E, (b + 1) * ESB);
        for (int e = b * ESB + (int)threadIdx.x; e < e1; e += 256)
            atomicAdd(&lh[dst[e] >> BSH], 1);                 // LDS atomic only
        __syncthreads();
        for (int i = (int)threadIdx.x; i < NB; i += 256) hist[(size_t)b * NB + i] = lh[i];
    } else if (b < SB + gC){
        int i4 = ((b - SB) * 256 + (int)threadIdx.x) * 4;
        if (i4 < nx){
            float4 v = *(const float4*)(xsrc + i4);
            ushort4 o; o.x = f2bf(v.x); o.y = f2bf(v.y); o.z = f2bf(v.z); o.w = f2bf(v.w);
            *(ushort4*)(xb + i4) = o;
            unsigned w = __builtin_amdgcn_cvt_pk_fp8_f32(v.x, v.y, 0, false);
            w = (unsigned)__builtin_amdgcn_cvt_pk_fp8_f32(v.z, v.w, (int)w, true);
            *(unsigned*)(x8 + i4) = w;
        }
    } else {
        // weight swizzle into MFMA fragment order:
        // Wf[((nt*8+kt)*64 + lane)*8 + j] = W[nt*16 + (lane&15)][kt*32 + (lane>>4)*8 + j]
        int i = (b - SB - gC) * 256 + (int)threadIdx.x;       // 320 blocks -> 81920 ushorts
        int f; ushort* dstp; int which;
        if (i < 32768){ f = i;          dstp = Wf1; which = 0; }
        else if (i < 65536){ f = i - 32768; dstp = Wfm; which = 1; }
        else { f = i - 65536; dstp = Wf2; which = 2; }
        int j    = f & 7;
        int lane = (f >> 3) & 63;
        int q    = f >> 9;
        int kt = q & 7, nt = q >> 3;
        int n = nt * 16 + (lane & 15);
        int k = kt * 32 + (lane >> 4) * 8 + j;
        float v;
        if (which == 0)      v = (k < 128) ? W1_l[(size_t)n * 128 + k] : W1_r[(size_t)n * 128 + (k - 128)];
        else if (which == 1) v = Wl1[(size_t)n * 256 + k];
        else                 v = (k < 128) ? W2_l[(size_t)n * 128 + k] : W2_r[(size_t)n * 128 + (k - 128)];
        dstp[f] = f2bf(v);
    }
}

// ---------------- scanA: per bucket, exclusive scan of hist over the 256 scatter blocks ----------------
__global__ __launch_bounds__(256) void k_scanA(const int* __restrict__ hist, int* __restrict__ base,
                                               int* __restrict__ bktcnt, int NB)
{
    __shared__ int s[256];
    const int b = (int)blockIdx.x, t = (int)threadIdx.x;
    const int v = hist[(size_t)t * NB + b];
    s[t] = v;
    __syncthreads();
    for (int ofs = 1; ofs < 256; ofs <<= 1){
        const int add = (t >= ofs) ? s[t - ofs] : 0;
        __syncthreads();
        s[t] += add;
        __syncthreads();
    }
    base[(size_t)t * NB + b] = s[t] - v;          // exclusive over blocks, within bucket b
    if (t == 255) bktcnt[b] = s[255];
}

// ---------------- scanB: exclusive scan over bucket totals (NB <= 2048) ----------------
__global__ __launch_bounds__(256) void k_scanB(const int* __restrict__ bktcnt, int* __restrict__ bktoff, int NB)
{
    __shared__ int s[256];
    const int t = (int)threadIdx.x;
    int v[8], p[8]; int run = 0;
    #pragma unroll
    for (int k = 0; k < 8; k++){
        const int id = t * 8 + k;
        v[k] = (id < NB) ? bktcnt[id] : 0;
        p[k] = run; run += v[k];
    }
    s[t] = run;
    __syncthreads();
    for (int ofs = 1; ofs < 256; ofs <<= 1){
        const int add = (t >= ofs) ? s[t - ofs] : 0;
        __syncthreads();
        s[t] += add;
        __syncthreads();
    }
    const int excl = (t > 0) ? s[t - 1] : 0;
    #pragma unroll
    for (int k = 0; k < 8; k++){
        const int id = t * 8 + k;
        if (id <= NB) bktoff[id] = excl + p[k];   // bktoff[NB] == E
    }
}

// ---------------- scatter: bucket-sort edges into packed records; LDS-only rank atomics ----------------
__global__ __launch_bounds__(256) void k_scatter(
    const int* __restrict__ dst, const int* __restrict__ src,
    const int* __restrict__ base, const int* __restrict__ bktoff,
    unsigned* __restrict__ recs, int E, int ESB, int NB)
{
    __shared__ int gbase[NBMAX];
    __shared__ int h2[NBMAX];
    const int h = (int)blockIdx.x;
    for (int i = (int)threadIdx.x; i < NB; i += 256){
        gbase[i] = bktoff[i] + base[(size_t)h * NB + i];
        h2[i] = 0;
    }
    __syncthreads();
    const int e1 = min(E, (h + 1) * ESB);
    for (int e = h * ESB + (int)threadIdx.x; e < e1; e += 256){
        const int d = dst[e], s = src[e];
        const int bk = d >> BSH;
        const int r  = atomicAdd(&h2[bk], 1);     // LDS atomic
        recs[gbase[bk] + r] = (unsigned)s | ((unsigned)(d & (BWD - 1)) << 16);
    }
}

// ---------------- mean aggregation over fp8 features: one block per 32-node bucket ----------------
// LDS fp32 accumulator [32][132] (pad decorrelates rows across banks); edge gathers identical to
// before (16 lanes x 8B per edge row); degree counted in LDS; no CSR, no per-node rank.

__global__ __launch_bounds__(256) void k_agg8(
    const unsigned char* __restrict__ feat8, const unsigned* __restrict__ recs,
    const int* __restrict__ bktoff, ushort* __restrict__ agg, int N)
{
    __shared__ float acc[BWD * 132];
    __shared__ int   cnt[BWD];
    const int b = (int)blockIdx.x;
    const int t = (int)threadIdx.x;
    for (int i = t; i < BWD * 132; i += 256) acc[i] = 0.f;
    if (t < BWD) cnt[t] = 0;
    __syncthreads();

    const int start = bktoff[b], end = bktoff[b + 1];
    const int wave = t >> 6, lane = t & 63;
    const int grp = lane >> 4, sub = lane & 15;   // 16 lanes per edge; lane sub covers cols [8*sub, 8*sub+8)

    for (int eb = start + wave * 64; eb < end; eb += 256){
        const int m = min(64, end - eb);
        int idx = (lane < m) ? (int)recs[eb + lane] : -1;
        const int iters = (m + 3) >> 2;
        for (int j = 0; j < iters; j++){
            int rec = __shfl(idx, j * 4 + grp);
            const bool valid = (rec != -1);
            const unsigned msk = valid ? 0xffffffffu : 0u;
            const int s    = valid ? (rec & 0xffff) : 0;
            const int dloc = (rec >> 16) & (BWD - 1);
            uint2 raw = *(const uint2*)(feat8 + (size_t)s * FDIM + sub * 8);
            raw.x &= msk; raw.y &= msk;           // fp8 0x00 == 0.0
            f32x2 f0 = __builtin_amdgcn_cvt_pk_f32_fp8((int)raw.x, false);
            f32x2 f1 = __builtin_amdgcn_cvt_pk_f32_fp8((int)raw.x, true);
            f32x2 f2 = __builtin_amdgcn_cvt_pk_f32_fp8((int)raw.y, false);
            f32x2 f3 = __builtin_amdgcn_cvt_pk_f32_fp8((int)raw.y, true);
            float* arow = acc + dloc * 132 + sub * 8;
            atomicAdd(&arow[0], f0.x); atomicAdd(&arow[1], f0.y);
            atomicAdd(&arow[2], f1.x); atomicAdd(&arow[3], f1.y);
            atomicAdd(&arow[4], f2.x); atomicAdd(&arow[5], f2.y);
            atomicAdd(&arow[6], f3.x); atomicAdd(&arow[7], f3.y);
            if (sub == 0 && valid) atomicAdd(&cnt[dloc], 1);
        }
    }
    __syncthreads();

    const int nn  = min(BWD, N - b * BWD);
    const int row = t >> 3;
    const int c   = (t & 7) * 16;
    if (row < nn){
        const int node = b * BWD + row;
        const float inv = 1.f / (float)max(cnt[row], 1);
        const float* ar = acc + row * 132 + c;
        uint4 o0, o1;
        o0.x = (unsigned)f2bf(ar[0]  * inv) | ((unsigned)f2bf(ar[1]  * inv) << 16);
        o0.y = (unsigned)f2bf(ar[2]  * inv) | ((unsigned)f2bf(ar[3]  * inv) << 16);
        o0.z = (unsigned)f2bf(ar[4]  * inv) | ((unsigned)f2bf(ar[5]  * inv) << 16);
        o0.w = (unsigned)f2bf(ar[6]  * inv) | ((unsigned)f2bf(ar[7]  * inv) << 16);
        o1.x = (unsigned)f2bf(ar[8]  * inv) | ((unsigned)f2bf(ar[9]  * inv) << 16);
        o1.y = (unsigned)f2bf(ar[10] * inv) | ((unsigned)f2bf(ar[11] * inv) << 16);
        o1.z = (unsigned)f2bf(ar[12] * inv) | ((unsigned)f2bf(ar[13] * inv) << 16);
        o1.w = (unsigned)f2bf(ar[14] * inv) | ((unsigned)f2bf(ar[15] * inv) << 16);
        *(uint4*)(agg + (size_t)node * FDIM + c)     = o0;
        *(uint4*)(agg + (size_t)node * FDIM + c + 8) = o1;
    }
}

// ---------------- LDS-weight linear (weights staged once/block, conflict-free ds_read_b128) ----------------
// Grid 512 x 4 waves; 2 row-tiles per wave. FP8OUT additionally emits fp8 copy of the output.

template<int NT, bool NORM, bool RELU, bool OUTF32, bool FP8OUT>
__global__ __launch_bounds__(256) void k_lin(
    const ushort* __restrict__ A1, const ushort* __restrict__ A2,
    const ushort* __restrict__ Wf, const float* __restrict__ bias,
    void* __restrict__ outv, unsigned char* __restrict__ out8, int N, int TILES)
{
    __shared__ __align__(16) ushort WS[NT*8*64*8];   // NT*8 KB
    {
        const uint4* wsrc = (const uint4*)Wf;
        uint4* wdst = (uint4*)WS;
        for (int i = threadIdx.x; i < NT*512; i += 256) wdst[i] = wsrc[i];
    }
    __syncthreads();

    const int wave = threadIdx.x >> 6, lane = threadIdx.x & 63;
    const int m = lane & 15, quad = lane >> 4;
    const ushort* WSl = WS + lane*8;    // frag (nt,kt) at WSl + (nt*8+kt)*512

    const int g  = blockIdx.x*4 + wave;          // 0..2047
    const int t0 = g, t1 = g + 2048;
    const bool has2 = (t1 < TILES);

    bf16x8 af0[8], af1[8];
    {
        int r0 = min(t0*16 + m, N-1);
        const ushort* p1 = A1 + (size_t)r0*FDIM + quad*8;
        const ushort* p2 = A2 + (size_t)r0*FDIM + quad*8;
        #pragma unroll
        for (int c = 0; c < 4; c++){
            af0[c]   = *(const bf16x8*)(p1 + c*32);
            af0[4+c] = *(const bf16x8*)(p2 + c*32);
        }
    }
    if (has2){
        int r1 = min(t1*16 + m, N-1);
        const ushort* p1 = A1 + (size_t)r1*FDIM + quad*8;
        const ushort* p2 = A2 + (size_t)r1*FDIM + quad*8;
        #pragma unroll
        for (int c = 0; c < 4; c++){
            af1[c]   = *(const bf16x8*)(p1 + c*32);
            af1[4+c] = *(const bf16x8*)(p2 + c*32);
        }
    }

    f32x4 acc0[NT], acc1[NT];
    #pragma unroll
    for (int nt = 0; nt < NT; nt++){ acc0[nt] = f32x4{0.f,0.f,0.f,0.f}; acc1[nt] = f32x4{0.f,0.f,0.f,0.f}; }

    if (has2){
        #pragma unroll
        for (int kt = 0; kt < 8; kt++)
            #pragma unroll
            for (int nt = 0; nt < NT; nt++){
                bf16x8 bfr = *(const bf16x8*)(WSl + (nt*8+kt)*512);
                acc0[nt] = __builtin_amdgcn_mfma_f32_16x16x32_bf16(af0[kt], bfr, acc0[nt], 0, 0, 0);
                acc1[nt] = __builtin_amdgcn_mfma_f32_16x16x32_bf16(af1[kt], bfr, acc1[nt], 0, 0, 0);
            }
    } else {
        #pragma unroll
        for (int kt = 0; kt < 8; kt++)
            #pragma unroll
            for (int nt = 0; nt < NT; nt++){
                bf16x8 bfr = *(const bf16x8*)(WSl + (nt*8+kt)*512);
                acc0[nt] = __builtin_amdgcn_mfma_f32_16x16x32_bf16(af0[kt], bfr, acc0[nt], 0, 0, 0);
            }
    }

    auto epi = [&](int t, f32x4* acc){
        #pragma unroll
        for (int nt = 0; nt < NT; nt++){
            float b = bias[nt*16 + m];
            acc[nt][0]+=b; acc[nt][1]+=b; acc[nt][2]+=b; acc[nt][3]+=b;
        }
        if (NORM){
            #pragma unroll
            for (int reg = 0; reg < 4; reg++){
                float ss = 0.f;
                #pragma unroll
                for (int nt = 0; nt < NT; nt++) ss += acc[nt][reg]*acc[nt][reg];
                ss += __shfl_xor(ss,1); ss += __shfl_xor(ss,2); ss += __shfl_xor(ss,4); ss += __shfl_xor(ss,8);
                float invn = 1.f / fmaxf(sqrtf(ss), 1e-12f);
                #pragma unroll
                for (int nt = 0; nt < NT; nt++) acc[nt][reg] *= invn;
            }
        }
        if (RELU){
            #pragma unroll
            for (int nt = 0; nt < NT; nt++){
                acc[nt][0]=fmaxf(acc[nt][0],0.f); acc[nt][1]=fmaxf(acc[nt][1],0.f);
                acc[nt][2]=fmaxf(acc[nt][2],0.f); acc[nt][3]=fmaxf(acc[nt][3],0.f);
            }
        }
        #pragma unroll
        for (int reg = 0; reg < 4; reg++){
            int row = t*16 + quad*4 + reg;
            if (row < N){
                if (OUTF32){
                    float* o = (float*)outv + (size_t)row*(NT*16) + m;
                    #pragma unroll
                    for (int nt = 0; nt < NT; nt++) o[nt*16] = acc[nt][reg];
                } else {
                    ushort* o = (ushort*)outv + (size_t)row*(NT*16) + m;
                    #pragma unroll
                    for (int nt = 0; nt < NT; nt++) o[nt*16] = f2bf(acc[nt][reg]);
                    if (FP8OUT){
                        unsigned char* o8 = out8 + (size_t)row*(NT*16) + m;
                        #pragma unroll
                        for (int nt = 0; nt < NT; nt++) o8[nt*16] = f2fp8(acc[nt][reg]);
                    }
                }
            }
        }
    };
    epi(t0, acc0);
    if (has2) epi(t1, acc1);
}

// ---------------- launch ----------------

extern "C" void kernel_launch(void* const* d_in, const int* in_sizes, int n_in,
                              void* d_out, int out_size, void* d_ws, size_t ws_size,
                              hipStream_t stream)
{
    const float* x    = (const float*)d_in[0];
    const int*   ei   = (const int*)  d_in[1];
    const float* W1_l = (const float*)d_in[2];
    const float* b1_l = (const float*)d_in[3];
    const float* W1_r = (const float*)d_in[4];
    const float* Wl1  = (const float*)d_in[5];
    const float* bl1  = (const float*)d_in[6];
    const float* W2_l = (const float*)d_in[7];
    const float* b2_l = (const float*)d_in[8];
    const float* W2_r = (const float*)d_in[9];
    float* out = (float*)d_out;

    const int N = in_sizes[0] / FDIM;   // 50000
    const int E = in_sizes[1] / 2;      // 800000

    const int* src = ei;
    const int* dst = ei + E;

    char* p = (char*)d_ws;
    auto carve = [&](size_t bytes) -> void* {
        void* r = (void*)p;
        p += (bytes + 255) & ~(size_t)255;
        return r;
    };

    const int SB  = 256;                         // scatter blocks (must be 256: k_scanA maps thread->block)
    const int ESB = (E + SB - 1) / SB;           // 3125 edges per block
    const int NB  = (N + BWD - 1) >> BSH;        // 1563 buckets of 32 nodes

    int*           hist    = (int*)     carve((size_t)SB * NB * 4);
    int*           base    = (int*)     carve((size_t)SB * NB * 4);
    int*           bktcnt  = (int*)     carve((size_t)NB * 4);
    int*           bktoff  = (int*)     carve((size_t)(NB + 1) * 4);
    unsigned*      recs    = (unsigned*)carve((size_t)E * 4);
    ushort*        xb      = (ushort*)  carve((size_t)N * FDIM * 2);
    ushort*        h1b     = (ushort*)  carve((size_t)N * FDIM * 2);
    ushort*        hb      = (ushort*)  carve((size_t)N * FDIM * 2);
    ushort*        aggb    = (ushort*)  carve((size_t)N * FDIM * 2);
    unsigned char* x8      = (unsigned char*)carve((size_t)N * FDIM);
    unsigned char* h8      = (unsigned char*)carve((size_t)N * FDIM);
    ushort*        Wf1     = (ushort*)  carve((size_t)32768 * 2);
    ushort*        Wfm     = (ushort*)  carve((size_t)32768 * 2);
    ushort*        Wf2     = (ushort*)  carve((size_t)16384 * 2);

    const int gCast = (N * FDIM / 4 + 255) / 256;     // 6250
    const int TILES = (N + 15) / 16;                  // 3125
    const int gLin  = 512;                            // 2048 wave slots, 2 tiles/wave

    // pass 1: bucket histograms | x->bf16+fp8 | weight swizzle (fused, no atomics, no memset needed)
    k_pass1<<<SB + gCast + 320, 256, 0, stream>>>(dst, hist, E, ESB, NB, SB,
                                                  x, xb, x8, N*FDIM, gCast,
                                                  W1_l, W1_r, Wl1, W2_l, W2_r, Wf1, Wfm, Wf2);
    k_scanA<<<NB, 256, 0, stream>>>(hist, base, bktcnt, NB);
    k_scanB<<<1,  256, 0, stream>>>(bktcnt, bktoff, NB);
    k_scatter<<<SB, 256, 0, stream>>>(dst, src, base, bktoff, recs, E, ESB, NB);

    // layer 1: h1 = relu(norm([agg(x)|x] @ W1^T + b1))
    k_agg8<<<NB, 256, 0, stream>>>(x8, recs, bktoff, aggb, N);
    k_lin<8, true,  true,  false, false><<<gLin, 256, 0, stream>>>(aggb, xb, Wf1, b1_l, h1b, nullptr, N, TILES);

    // mid: h = relu([x|h1] @ Wl1^T + bl1)   (also emits fp8 copy for layer-2 gather)
    k_lin<8, false, true,  false, true ><<<gLin, 256, 0, stream>>>(xb, h1b, Wfm, bl1, hb, h8, N, TILES);

    // layer 2: out = norm([agg(h)|h] @ W2^T + b2)  (fp32 out)
    k_agg8<<<NB, 256, 0, stream>>>(h8, recs, bktoff, aggb, N);
    k_lin<4, true,  false, true,  false><<<gLin, 256, 0, stream>>>(aggb, hb, Wf2, b2_l, out, nullptr, N, TILES);
}

// Round 2
// 215.303 us; speedup vs baseline: 6.3701x; 6.3701x over previous
//
#include <hip/hip_runtime.h>
#include <hip/hip_bf16.h>

constexpr int FDIM  = 128;
constexpr int BSH   = 5;      // 32 nodes per bucket
constexpr int BWD   = 32;
constexpr int NBMAX = 2048;   // supports N <= 65536 (N = 50000)
constexpr int CAP   = 3072;   // per-bucket record capacity in k_agg8 (mean 512, sd ~23 -> never exceeded)

typedef __attribute__((ext_vector_type(8))) short bf16x8;   // 8 bf16 = 4 VGPRs
typedef __attribute__((ext_vector_type(4))) float f32x4;
typedef __attribute__((ext_vector_type(2))) float f32x2;

static __device__ __forceinline__ ushort f2bf(float f){
    union { float f; unsigned u; } v; v.f = f;
    unsigned r = v.u + 0x7fffu + ((v.u >> 16) & 1u);   // RNE
    return (ushort)(r >> 16);
}
static __device__ __forceinline__ unsigned char f2fp8(float f){
    return (unsigned char)(__builtin_amdgcn_cvt_pk_fp8_f32(f, f, 0, false) & 0xff);
}

// ---------------- pass 1 (fused): per-block bucket histogram | x cast | weight swizzle ----------------
// Bucket histogram: dst read ONCE, all counting in LDS, dense [SB][NB] count matrix out. No global atomics.

__global__ __launch_bounds__(256) void k_pass1(
    const int* __restrict__ dst, int* __restrict__ hist,
    int E, int ESB, int NB, int SB,
    const float* __restrict__ xsrc, ushort* __restrict__ xb, unsigned char* __restrict__ x8, int nx, int gC,
    const float* __restrict__ W1_l, const float* __restrict__ W1_r,
    const float* __restrict__ Wl1,
    const float* __restrict__ W2_l, const float* __restrict__ W2_r,
    ushort* __restrict__ Wf1, ushort* __restrict__ Wfm, ushort* __restrict__ Wf2)
{
    const int b = (int)blockIdx.x;
    if (b < SB){
        __shared__ int lh[NBMAX];
        for (int i = (int)threadIdx.x; i < NB; i += 256) lh[i] = 0;
        __syncthreads();
        const int e1 = min(E, (b + 1) * ESB);
        for (int e = b * ESB + (int)threadIdx.x; e < e1; e += 256)
            atomicAdd(&lh[dst[e] >> BSH], 1);                 // LDS atomic only
        __syncthreads();
        for (int i = (int)threadIdx.x; i < NB; i += 256) hist[(size_t)b * NB + i] = lh[i];
    } else if (b < SB + gC){
        int i4 = ((b - SB) * 256 + (int)threadIdx.x) * 4;
        if (i4 < nx){
            float4 v = *(const float4*)(xsrc + i4);
            ushort4 o; o.x = f2bf(v.x); o.y = f2bf(v.y); o.z = f2bf(v.z); o.w = f2bf(v.w);
            *(ushort4*)(xb + i4) = o;
            unsigned w = __builtin_amdgcn_cvt_pk_fp8_f32(v.x, v.y, 0, false);
            w = (unsigned)__builtin_amdgcn_cvt_pk_fp8_f32(v.z, v.w, (int)w, true);
            *(unsigned*)(x8 + i4) = w;
        }
    } else {
        // weight swizzle into MFMA fragment order:
        // Wf[((nt*8+kt)*64 + lane)*8 + j] = W[nt*16 + (lane&15)][kt*32 + (lane>>4)*8 + j]
        int i = (b - SB - gC) * 256 + (int)threadIdx.x;       // 320 blocks -> 81920 ushorts
        int f; ushort* dstp; int which;
        if (i < 32768){ f = i;          dstp = Wf1; which = 0; }
        else if (i < 65536){ f = i - 32768; dstp = Wfm; which = 1; }
        else { f = i - 65536; dstp = Wf2; which = 2; }
        int j    = f & 7;
        int lane = (f >> 3) & 63;
        int q    = f >> 9;
        int kt = q & 7, nt = q >> 3;
        int n = nt * 16 + (lane & 15);
        int k = kt * 32 + (lane >> 4) * 8 + j;
        float v;
        if (which == 0)      v = (k < 128) ? W1_l[(size_t)n * 128 + k] : W1_r[(size_t)n * 128 + (k - 128)];
        else if (which == 1) v = Wl1[(size_t)n * 256 + k];
        else                 v = (k < 128) ? W2_l[(size_t)n * 128 + k] : W2_r[(size_t)n * 128 + (k - 128)];
        dstp[f] = f2bf(v);
    }
}

// ---------------- scanA: per bucket, exclusive scan of hist over the 256 scatter blocks ----------------
__global__ __launch_bounds__(256) void k_scanA(const int* __restrict__ hist, int* __restrict__ base,
                                               int* __restrict__ bktcnt, int NB)
{
    __shared__ int s[256];
    const int b = (int)blockIdx.x, t = (int)threadIdx.x;
    const int v = hist[(size_t)t * NB + b];
    s[t] = v;
    __syncthreads();
    for (int ofs = 1; ofs < 256; ofs <<= 1){
        const int add = (t >= ofs) ? s[t - ofs] : 0;
        __syncthreads();
        s[t] += add;
        __syncthreads();
    }
    base[(size_t)t * NB + b] = s[t] - v;          // exclusive over blocks, within bucket b
    if (t == 255) bktcnt[b] = s[255];
}

// ---------------- scanB: exclusive scan over bucket totals (NB <= 2048) ----------------
__global__ __launch_bounds__(256) void k_scanB(const int* __restrict__ bktcnt, int* __restrict__ bktoff, int NB)
{
    __shared__ int s[256];
    const int t = (int)threadIdx.x;
    int v[8], p[8]; int run = 0;
    #pragma unroll
    for (int k = 0; k < 8; k++){
        const int id = t * 8 + k;
        v[k] = (id < NB) ? bktcnt[id] : 0;
        p[k] = run; run += v[k];
    }
    s[t] = run;
    __syncthreads();
    for (int ofs = 1; ofs < 256; ofs <<= 1){
        const int add = (t >= ofs) ? s[t - ofs] : 0;
        __syncthreads();
        s[t] += add;
        __syncthreads();
    }
    const int excl = (t > 0) ? s[t - 1] : 0;
    #pragma unroll
    for (int k = 0; k < 8; k++){
        const int id = t * 8 + k;
        if (id <= NB) bktoff[id] = excl + p[k];   // bktoff[NB] == E
    }
}

// ---------------- scatter: bucket-sort edges into packed records; LDS-only rank atomics ----------------
__global__ __launch_bounds__(256) void k_scatter(
    const int* __restrict__ dst, const int* __restrict__ src,
    const int* __restrict__ base, const int* __restrict__ bktoff,
    unsigned* __restrict__ recs, int E, int ESB, int NB)
{
    __shared__ int gbase[NBMAX];
    __shared__ int h2[NBMAX];
    const int h = (int)blockIdx.x;
    for (int i = (int)threadIdx.x; i < NB; i += 256){
        gbase[i] = bktoff[i] + base[(size_t)h * NB + i];
        h2[i] = 0;
    }
    __syncthreads();
    const int e1 = min(E, (h + 1) * ESB);
    for (int e = h * ESB + (int)threadIdx.x; e < e1; e += 256){
        const int d = dst[e], s = src[e];
        const int bk = d >> BSH;
        const int r  = atomicAdd(&h2[bk], 1);     // LDS atomic
        recs[gbase[bk] + r] = (unsigned)s | ((unsigned)(d & (BWD - 1)) << 16);
    }
}

// ---------------- mean aggregation over fp8 features ----------------
// One block per 32-node bucket. Phase 1: tiny in-LDS counting sort of the bucket's records by
// local node (~512 recs, 32 counters, 2 LDS atomics/edge — off the gather critical path).
// Phase 2: per-node register-accumulate wave gather (the proven round-0 structure: 16 lanes/edge,
// 4 gather loads in flight per wave, shfl-xor reduce). Edge indices come from LDS, not global CSR.

__global__ __launch_bounds__(256) void k_agg8(
    const unsigned char* __restrict__ feat8, const unsigned* __restrict__ recs,
    const int* __restrict__ bktoff, ushort* __restrict__ agg, int N)
{
    __shared__ unsigned lrec[CAP];
    __shared__ int ldeg[BWD], loff[BWD + 1], lpos[BWD];

    const int b = (int)blockIdx.x;
    const int t = (int)threadIdx.x;
    const int wave = t >> 6, lane = t & 63;
    const int grp = lane >> 4, sub = lane & 15;   // 16 lanes per edge; lane sub covers cols [8*sub, 8*sub+8)

    const int start = bktoff[b];
    const int cnt   = bktoff[b + 1] - start;

    if (t < BWD){ ldeg[t] = 0; lpos[t] = 0; }
    __syncthreads();

    auto accum = [&](uint2 raw, float& a0, float& a1, float& a2, float& a3,
                                float& a4, float& a5, float& a6, float& a7){
        f32x2 f;
        f = __builtin_amdgcn_cvt_pk_f32_fp8((int)raw.x, false); a0 += f.x; a1 += f.y;
        f = __builtin_amdgcn_cvt_pk_f32_fp8((int)raw.x, true);  a2 += f.x; a3 += f.y;
        f = __builtin_amdgcn_cvt_pk_f32_fp8((int)raw.y, false); a4 += f.x; a5 += f.y;
        f = __builtin_amdgcn_cvt_pk_f32_fp8((int)raw.y, true);  a6 += f.x; a7 += f.y;
    };

    auto writeout = [&](int node, int d, float a0, float a1, float a2, float a3,
                                          float a4, float a5, float a6, float a7){
        a0 += __shfl_xor(a0,16); a1 += __shfl_xor(a1,16); a2 += __shfl_xor(a2,16); a3 += __shfl_xor(a3,16);
        a4 += __shfl_xor(a4,16); a5 += __shfl_xor(a5,16); a6 += __shfl_xor(a6,16); a7 += __shfl_xor(a7,16);
        a0 += __shfl_xor(a0,32); a1 += __shfl_xor(a1,32); a2 += __shfl_xor(a2,32); a3 += __shfl_xor(a3,32);
        a4 += __shfl_xor(a4,32); a5 += __shfl_xor(a5,32); a6 += __shfl_xor(a6,32); a7 += __shfl_xor(a7,32);
        if (grp == 0){
            float inv = 1.f / (float)(d > 1 ? d : 1);
            uint4 r;
            r.x = (unsigned)f2bf(a0*inv) | ((unsigned)f2bf(a1*inv) << 16);
            r.y = (unsigned)f2bf(a2*inv) | ((unsigned)f2bf(a3*inv) << 16);
            r.z = (unsigned)f2bf(a4*inv) | ((unsigned)f2bf(a5*inv) << 16);
            r.w = (unsigned)f2bf(a6*inv) | ((unsigned)f2bf(a7*inv) << 16);
            *(uint4*)(agg + (size_t)node*FDIM + sub*8) = r;
        }
    };

    if (cnt <= CAP){
        // ---- in-LDS counting sort by local node ----
        for (int i = t; i < cnt; i += 256) atomicAdd(&ldeg[(recs[start + i] >> 16) & (BWD-1)], 1);
        __syncthreads();
        if (t == 0){
            int r = 0;
            #pragma unroll
            for (int j = 0; j < BWD; j++){ loff[j] = r; r += ldeg[j]; }
            loff[BWD] = r;
        }
        __syncthreads();
        for (int i = t; i < cnt; i += 256){
            unsigned rec = recs[start + i];
            int dl = (rec >> 16) & (BWD-1);
            int r  = atomicAdd(&lpos[dl], 1);
            lrec[loff[dl] + r] = rec;
        }
        __syncthreads();

        // ---- per-node wave gather (4 loads in flight) ----
        for (int nl = wave; nl < BWD; nl += 4){
            const int node = b*BWD + nl;
            if (node >= N) break;
            const int o = loff[nl], d = ldeg[nl];
            float a0=0.f,a1=0.f,a2=0.f,a3=0.f,a4=0.f,a5=0.f,a6=0.f,a7=0.f;

            for (int base2 = 0; base2 < d; base2 += 64){
                int m2 = min(64, d - base2);
                int idx = (lane < m2) ? (int)(lrec[o + base2 + lane] & 0xffffu) : -1;
                int iters = (m2 + 3) >> 2;
                int j = 0;
                for (; j + 4 <= iters; j += 4){
                    int s0 = __shfl(idx, (j+0)*4 + grp);
                    int s1 = __shfl(idx, (j+1)*4 + grp);
                    int s2 = __shfl(idx, (j+2)*4 + grp);
                    int s3 = __shfl(idx, (j+3)*4 + grp);
                    unsigned m0 = (s0 >= 0) ? 0xffffffffu : 0u;  int p0 = (s0 >= 0) ? s0 : 0;
                    unsigned m1 = (s1 >= 0) ? 0xffffffffu : 0u;  int p1 = (s1 >= 0) ? s1 : 0;
                    unsigned m2_ = (s2 >= 0) ? 0xffffffffu : 0u; int p2 = (s2 >= 0) ? s2 : 0;
                    unsigned m3 = (s3 >= 0) ? 0xffffffffu : 0u;  int p3 = (s3 >= 0) ? s3 : 0;
                    uint2 r0 = *(const uint2*)(feat8 + (size_t)p0*FDIM + sub*8);
                    uint2 r1 = *(const uint2*)(feat8 + (size_t)p1*FDIM + sub*8);
                    uint2 r2 = *(const uint2*)(feat8 + (size_t)p2*FDIM + sub*8);
                    uint2 r3 = *(const uint2*)(feat8 + (size_t)p3*FDIM + sub*8);
                    r0.x &= m0; r0.y &= m0;  r1.x &= m1; r1.y &= m1;   // fp8 0x00 == 0.0
                    r2.x &= m2_; r2.y &= m2_; r3.x &= m3; r3.y &= m3;
                    accum(r0,a0,a1,a2,a3,a4,a5,a6,a7); accum(r1,a0,a1,a2,a3,a4,a5,a6,a7);
                    accum(r2,a0,a1,a2,a3,a4,a5,a6,a7); accum(r3,a0,a1,a2,a3,a4,a5,a6,a7);
                }
                for (; j < iters; j++){
                    int s = __shfl(idx, j*4 + grp);
                    unsigned msk = (s >= 0) ? 0xffffffffu : 0u;
                    int sr = (s >= 0) ? s : 0;
                    uint2 raw = *(const uint2*)(feat8 + (size_t)sr*FDIM + sub*8);
                    raw.x &= msk; raw.y &= msk;
                    accum(raw,a0,a1,a2,a3,a4,a5,a6,a7);
                }
            }
            writeout(node, d, a0,a1,a2,a3,a4,a5,a6,a7);
        }
    } else {
        // ---- fallback (bucket overflow; correct for any input, never triggered for this bench) ----
        for (int nl = wave; nl < BWD; nl += 4){
            const int node = b*BWD + nl;
            if (node >= N) break;
            float a0=0.f,a1=0.f,a2=0.f,a3=0.f,a4=0.f,a5=0.f,a6=0.f,a7=0.f;
            int d = 0;
            for (int i = 0; i < cnt; i++){
                unsigned rec = recs[start + i];               // uniform -> broadcast
                if (((rec >> 16) & (BWD-1)) == (unsigned)nl){
                    d++;
                    if (grp == 0){
                        uint2 raw = *(const uint2*)(feat8 + (size_t)(rec & 0xffffu)*FDIM + sub*8);
                        accum(raw,a0,a1,a2,a3,a4,a5,a6,a7);
                    }
                }
            }
            writeout(node, d, a0,a1,a2,a3,a4,a5,a6,a7);   // non-grp0 lanes hold zeros
        }
    }
}

// ---------------- LDS-weight linear (weights staged once/block, conflict-free ds_read_b128) ----------------
// Grid 512 x 4 waves; 2 row-tiles per wave. FP8OUT additionally emits fp8 copy of the output.

template<int NT, bool NORM, bool RELU, bool OUTF32, bool FP8OUT>
__global__ __launch_bounds__(256) void k_lin(
    const ushort* __restrict__ A1, const ushort* __restrict__ A2,
    const ushort* __restrict__ Wf, const float* __restrict__ bias,
    void* __restrict__ outv, unsigned char* __restrict__ out8, int N, int TILES)
{
    __shared__ __align__(16) ushort WS[NT*8*64*8];   // NT*8 KB
    {
        const uint4* wsrc = (const uint4*)Wf;
        uint4* wdst = (uint4*)WS;
        for (int i = threadIdx.x; i < NT*512; i += 256) wdst[i] = wsrc[i];
    }
    __syncthreads();

    const int wave = threadIdx.x >> 6, lane = threadIdx.x & 63;
    const int m = lane & 15, quad = lane >> 4;
    const ushort* WSl = WS + lane*8;    // frag (nt,kt) at WSl + (nt*8+kt)*512

    const int g  = blockIdx.x*4 + wave;          // 0..2047
    const int t0 = g, t1 = g + 2048;
    const bool has2 = (t1 < TILES);

    bf16x8 af0[8], af1[8];
    {
        int r0 = min(t0*16 + m, N-1);
        const ushort* p1 = A1 + (size_t)r0*FDIM + quad*8;
        const ushort* p2 = A2 + (size_t)r0*FDIM + quad*8;
        #pragma unroll
        for (int c = 0; c < 4; c++){
            af0[c]   = *(const bf16x8*)(p1 + c*32);
            af0[4+c] = *(const bf16x8*)(p2 + c*32);
        }
    }
    if (has2){
        int r1 = min(t1*16 + m, N-1);
        const ushort* p1 = A1 + (size_t)r1*FDIM + quad*8;
        const ushort* p2 = A2 + (size_t)r1*FDIM + quad*8;
        #pragma unroll
        for (int c = 0; c < 4; c++){
            af1[c]   = *(const bf16x8*)(p1 + c*32);
            af1[4+c] = *(const bf16x8*)(p2 + c*32);
        }
    }

    f32x4 acc0[NT], acc1[NT];
    #pragma unroll
    for (int nt = 0; nt < NT; nt++){ acc0[nt] = f32x4{0.f,0.f,0.f,0.f}; acc1[nt] = f32x4{0.f,0.f,0.f,0.f}; }

    if (has2){
        #pragma unroll
        for (int kt = 0; kt < 8; kt++)
            #pragma unroll
            for (int nt = 0; nt < NT; nt++){
                bf16x8 bfr = *(const bf16x8*)(WSl + (nt*8+kt)*512);
                acc0[nt] = __builtin_amdgcn_mfma_f32_16x16x32_bf16(af0[kt], bfr, acc0[nt], 0, 0, 0);
                acc1[nt] = __builtin_amdgcn_mfma_f32_16x16x32_bf16(af1[kt], bfr, acc1[nt], 0, 0, 0);
            }
    } else {
        #pragma unroll
        for (int kt = 0; kt < 8; kt++)
            #pragma unroll
            for (int nt = 0; nt < NT; nt++){
                bf16x8 bfr = *(const bf16x8*)(WSl + (nt*8+kt)*512);
                acc0[nt] = __builtin_amdgcn_mfma_f32_16x16x32_bf16(af0[kt], bfr, acc0[nt], 0, 0, 0);
            }
    }

    auto epi = [&](int t, f32x4* acc){
        #pragma unroll
        for (int nt = 0; nt < NT; nt++){
            float b = bias[nt*16 + m];
            acc[nt][0]+=b; acc[nt][1]+=b; acc[nt][2]+=b; acc[nt][3]+=b;
        }
        if (NORM){
            #pragma unroll
            for (int reg = 0; reg < 4; reg++){
                float ss = 0.f;
                #pragma unroll
                for (int nt = 0; nt < NT; nt++) ss += acc[nt][reg]*acc[nt][reg];
                ss += __shfl_xor(ss,1); ss += __shfl_xor(ss,2); ss += __shfl_xor(ss,4); ss += __shfl_xor(ss,8);
                float invn = 1.f / fmaxf(sqrtf(ss), 1e-12f);
                #pragma unroll
                for (int nt = 0; nt < NT; nt++) acc[nt][reg] *= invn;
            }
        }
        if (RELU){
            #pragma unroll
            for (int nt = 0; nt < NT; nt++){
                acc[nt][0]=fmaxf(acc[nt][0],0.f); acc[nt][1]=fmaxf(acc[nt][1],0.f);
                acc[nt][2]=fmaxf(acc[nt][2],0.f); acc[nt][3]=fmaxf(acc[nt][3],0.f);
            }
        }
        #pragma unroll
        for (int reg = 0; reg < 4; reg++){
            int row = t*16 + quad*4 + reg;
            if (row < N){
                if (OUTF32){
                    float* o = (float*)outv + (size_t)row*(NT*16) + m;
                    #pragma unroll
                    for (int nt = 0; nt < NT; nt++) o[nt*16] = acc[nt][reg];
                } else {
                    ushort* o = (ushort*)outv + (size_t)row*(NT*16) + m;
                    #pragma unroll
                    for (int nt = 0; nt < NT; nt++) o[nt*16] = f2bf(acc[nt][reg]);
                    if (FP8OUT){
                        unsigned char* o8 = out8 + (size_t)row*(NT*16) + m;
                        #pragma unroll
                        for (int nt = 0; nt < NT; nt++) o8[nt*16] = f2fp8(acc[nt][reg]);
                    }
                }
            }
        }
    };
    epi(t0, acc0);
    if (has2) epi(t1, acc1);
}

// ---------------- launch ----------------

extern "C" void kernel_launch(void* const* d_in, const int* in_sizes, int n_in,
                              void* d_out, int out_size, void* d_ws, size_t ws_size,
                              hipStream_t stream)
{
    const float* x    = (const float*)d_in[0];
    const int*   ei   = (const int*)  d_in[1];
    const float* W1_l = (const float*)d_in[2];
    const float* b1_l = (const float*)d_in[3];
    const float* W1_r = (const float*)d_in[4];
    const float* Wl1  = (const float*)d_in[5];
    const float* bl1  = (const float*)d_in[6];
    const float* W2_l = (const float*)d_in[7];
    const float* b2_l = (const float*)d_in[8];
    const float* W2_r = (const float*)d_in[9];
    float* out = (float*)d_out;

    const int N = in_sizes[0] / FDIM;   // 50000
    const int E = in_sizes[1] / 2;      // 800000

    const int* src = ei;
    const int* dst = ei + E;

    char* p = (char*)d_ws;
    auto carve = [&](size_t bytes) -> void* {
        void* r = (void*)p;
        p += (bytes + 255) & ~(size_t)255;
        return r;
    };

    const int SB  = 256;                         // scatter blocks (must be 256: k_scanA maps thread->block)
    const int ESB = (E + SB - 1) / SB;           // 3125 edges per block
    const int NB  = (N + BWD - 1) >> BSH;        // 1563 buckets of 32 nodes

    int*           hist    = (int*)     carve((size_t)SB * NB * 4);
    int*           base    = (int*)     carve((size_t)SB * NB * 4);
    int*           bktcnt  = (int*)     carve((size_t)NB * 4);
    int*           bktoff  = (int*)     carve((size_t)(NB + 1) * 4);
    unsigned*      recs    = (unsigned*)carve((size_t)E * 4);
    ushort*        xb      = (ushort*)  carve((size_t)N * FDIM * 2);
    ushort*        h1b     = (ushort*)  carve((size_t)N * FDIM * 2);
    ushort*        hb      = (ushort*)  carve((size_t)N * FDIM * 2);
    ushort*        aggb    = (ushort*)  carve((size_t)N * FDIM * 2);
    unsigned char* x8      = (unsigned char*)carve((size_t)N * FDIM);
    unsigned char* h8      = (unsigned char*)carve((size_t)N * FDIM);
    ushort*        Wf1     = (ushort*)  carve((size_t)32768 * 2);
    ushort*        Wfm     = (ushort*)  carve((size_t)32768 * 2);
    ushort*        Wf2     = (ushort*)  carve((size_t)16384 * 2);

    const int gCast = (N * FDIM / 4 + 255) / 256;     // 6250
    const int TILES = (N + 15) / 16;                  // 3125
    const int gLin  = 512;                            // 2048 wave slots, 2 tiles/wave

    // pass 1: bucket histograms | x->bf16+fp8 | weight swizzle (fused, no global atomics, no memset)
    k_pass1<<<SB + gCast + 320, 256, 0, stream>>>(dst, hist, E, ESB, NB, SB,
                                                  x, xb, x8, N*FDIM, gCast,
                                                  W1_l, W1_r, Wl1, W2_l, W2_r, Wf1, Wfm, Wf2);
    k_scanA<<<NB, 256, 0, stream>>>(hist, base, bktcnt, NB);
    k_scanB<<<1,  256, 0, stream>>>(bktcnt, bktoff, NB);
    k_scatter<<<SB, 256, 0, stream>>>(dst, src, base, bktoff, recs, E, ESB, NB);

    // layer 1: h1 = relu(norm([agg(x)|x] @ W1^T + b1))
    k_agg8<<<NB, 256, 0, stream>>>(x8, recs, bktoff, aggb, N);
    k_lin<8, true,  true,  false, false><<<gLin, 256, 0, stream>>>(aggb, xb, Wf1, b1_l, h1b, nullptr, N, TILES);

    // mid: h = relu([x|h1] @ Wl1^T + bl1)   (also emits fp8 copy for layer-2 gather)
    k_lin<8, false, true,  false, true ><<<gLin, 256, 0, stream>>>(xb, h1b, Wfm, bl1, hb, h8, N, TILES);

    // layer 2: out = norm([agg(h)|h] @ W2^T + b2)  (fp32 out)
    k_agg8<<<NB, 256, 0, stream>>>(h8, recs, bktoff, aggb, N);
    k_lin<4, true,  false, true,  false><<<gLin, 256, 0, stream>>>(aggb, hb, Wf2, b2_l, out, nullptr, N, TILES);
}

// Round 3
// 209.946 us; speedup vs baseline: 6.5326x; 1.0255x over previous
//
#include <hip/hip_runtime.h>
#include <hip/hip_bf16.h>

constexpr int FDIM  = 128;
constexpr int BSH   = 5;      // 32 nodes per bucket
constexpr int BWD   = 32;
constexpr int NBMAX = 2048;   // supports N <= 65536 (N = 50000)
constexpr int CAP   = 3072;   // per-bucket LDS record capacity in k_agg8 (incl. padding)
constexpr int CAPB  = 2048;   // fixed per-bucket global record capacity (mean 512, sd ~23)
constexpr int SAB   = 16;     // buckets per scanA block

typedef __attribute__((ext_vector_type(8))) short bf16x8;   // 8 bf16 = 4 VGPRs
typedef __attribute__((ext_vector_type(4))) float f32x4;
typedef __attribute__((ext_vector_type(2))) float f32x2;

static __device__ __forceinline__ ushort f2bf(float f){
    union { float f; unsigned u; } v; v.f = f;
    unsigned r = v.u + 0x7fffu + ((v.u >> 16) & 1u);   // RNE
    return (ushort)(r >> 16);
}
static __device__ __forceinline__ unsigned char f2fp8(float f){
    return (unsigned char)(__builtin_amdgcn_cvt_pk_fp8_f32(f, f, 0, false) & 0xff);
}

// ---------------- pass 1 (fused): bucket histogram | x cast | weight swizzle | dummy-row zero ----------------
// dst read ONCE, all counting in LDS, dense [SB][NB] count matrix out. No global atomics.
// Also zeroes row N of x8/h8 (the dummy row that padded gather records point at).

__global__ __launch_bounds__(256) void k_pass1(
    const int* __restrict__ dst, int* __restrict__ hist,
    int E, int ESB, int NB, int SB,
    const float* __restrict__ xsrc, ushort* __restrict__ xb,
    unsigned char* __restrict__ x8, unsigned char* __restrict__ h8, int nx, int gC,
    const float* __restrict__ W1_l, const float* __restrict__ W1_r,
    const float* __restrict__ Wl1,
    const float* __restrict__ W2_l, const float* __restrict__ W2_r,
    ushort* __restrict__ Wf1, ushort* __restrict__ Wfm, ushort* __restrict__ Wf2)
{
    const int b = (int)blockIdx.x;
    const int t = (int)threadIdx.x;
    if (b < SB){
        __shared__ int lh[NBMAX];
        for (int i = t; i < NB; i += 256) lh[i] = 0;
        __syncthreads();
        const int e1 = min(E, (b + 1) * ESB);
        for (int e = b * ESB + t; e < e1; e += 256)
            atomicAdd(&lh[dst[e] >> BSH], 1);                 // LDS atomic only
        __syncthreads();
        for (int i = t; i < NB; i += 256) hist[(size_t)b * NB + i] = lh[i];
    } else if (b < SB + gC){
        int i4 = ((b - SB) * 256 + t) * 4;
        if (i4 < nx){
            float4 v = *(const float4*)(xsrc + i4);
            ushort4 o; o.x = f2bf(v.x); o.y = f2bf(v.y); o.z = f2bf(v.z); o.w = f2bf(v.w);
            *(ushort4*)(xb + i4) = o;
            unsigned w = __builtin_amdgcn_cvt_pk_fp8_f32(v.x, v.y, 0, false);
            w = (unsigned)__builtin_amdgcn_cvt_pk_fp8_f32(v.z, v.w, (int)w, true);
            *(unsigned*)(x8 + i4) = w;
        }
    } else if (b < SB + gC + 320){
        // weight swizzle into MFMA fragment order:
        // Wf[((nt*8+kt)*64 + lane)*8 + j] = W[nt*16 + (lane&15)][kt*32 + (lane>>4)*8 + j]
        int i = (b - SB - gC) * 256 + t;                      // 320 blocks -> 81920 ushorts
        int f; ushort* dstp; int which;
        if (i < 32768){ f = i;          dstp = Wf1; which = 0; }
        else if (i < 65536){ f = i - 32768; dstp = Wfm; which = 1; }
        else { f = i - 65536; dstp = Wf2; which = 2; }
        int j    = f & 7;
        int lane = (f >> 3) & 63;
        int q    = f >> 9;
        int kt = q & 7, nt = q >> 3;
        int n = nt * 16 + (lane & 15);
        int k = kt * 32 + (lane >> 4) * 8 + j;
        float v;
        if (which == 0)      v = (k < 128) ? W1_l[(size_t)n * 128 + k] : W1_r[(size_t)n * 128 + (k - 128)];
        else if (which == 1) v = Wl1[(size_t)n * 256 + k];
        else                 v = (k < 128) ? W2_l[(size_t)n * 128 + k] : W2_r[(size_t)n * 128 + (k - 128)];
        dstp[f] = f2bf(v);
    } else {
        // zero the dummy row (index N) of both fp8 feature buffers
        if (t < 8)       *(uint4*)(x8 + (size_t)nx + t*16)      = make_uint4(0,0,0,0);
        else if (t < 16) *(uint4*)(h8 + (size_t)nx + (t-8)*16)  = make_uint4(0,0,0,0);
    }
}

// ---------------- scanA (tiled): per bucket, exclusive scan of hist over 256 scatter blocks ----------------
// Coalesced tile loads of [256][SAB], LDS transpose-scan, coalesced write-back + bucket totals.

__global__ __launch_bounds__(256) void k_scanA(const int* __restrict__ hist, int* __restrict__ base,
                                               int* __restrict__ bktcnt, int NB)
{
    __shared__ int T[256][SAB + 1];
    __shared__ int psum[16][SAB];
    const int t = (int)threadIdx.x;
    const int b0 = (int)blockIdx.x * SAB;
    const int cl = t & (SAB - 1);         // bucket within tile (load/store phases)
    const int rt = t >> 4;                // row group (16 rows per iteration)
    for (int it = 0; it < 16; it++){
        const int row = it * 16 + rt;
        T[row][cl] = (b0 + cl < NB) ? hist[(size_t)row * NB + b0 + cl] : 0;
    }
    __syncthreads();
    const int c = t & (SAB - 1), seg = t >> 4;   // 16 segs x 16 rows per bucket
    int s = 0;
    #pragma unroll
    for (int i = 0; i < 16; i++) s += T[seg * 16 + i][c];
    psum[seg][c] = s;
    __syncthreads();
    int off = 0;
    #pragma unroll
    for (int s2 = 0; s2 < 16; s2++){ int v = psum[s2][c]; if (s2 < seg) off += v; }
    int run = off;
    #pragma unroll
    for (int i = 0; i < 16; i++){
        const int idx = seg * 16 + i;
        const int v = T[idx][c];
        T[idx][c] = run;                  // exclusive over blocks, within bucket
        run += v;
    }
    if (seg == 15 && b0 + c < NB) bktcnt[b0 + c] = run;   // bucket total
    __syncthreads();
    for (int it = 0; it < 16; it++){
        const int row = it * 16 + rt;
        if (b0 + cl < NB) base[(size_t)row * NB + b0 + cl] = T[row][cl];
    }
}

// ---------------- scatter: bucket-sort edges into fixed-capacity regions; LDS-only rank atomics ----------------
__global__ __launch_bounds__(256) void k_scatter(
    const int* __restrict__ dst, const int* __restrict__ src,
    const int* __restrict__ base,
    unsigned* __restrict__ recs, int E, int ESB, int NB)
{
    __shared__ int gbase[NBMAX];
    __shared__ int h2[NBMAX];
    const int h = (int)blockIdx.x;
    for (int i = (int)threadIdx.x; i < NB; i += 256){
        gbase[i] = base[(size_t)h * NB + i];
        h2[i] = 0;
    }
    __syncthreads();
    const int e1 = min(E, (h + 1) * ESB);
    for (int e = h * ESB + (int)threadIdx.x; e < e1; e += 256){
        const int d = dst[e], s = src[e];
        const int bk = d >> BSH;
        const int r  = atomicAdd(&h2[bk], 1);     // LDS atomic
        const int pos = gbase[bk] + r;
        if (pos < CAPB)                           // overflow edges handled by agg fallback
            recs[(size_t)bk * CAPB + pos] = (unsigned)s | ((unsigned)(d & (BWD - 1)) << 16);
    }
}

// ---------------- mean aggregation over fp8 features ----------------
// One block per 32-node bucket. Phase 1: in-LDS counting sort, each node's segment PADDED to a
// multiple of 4 with dummy records (row N = zeroed) -> the gather loop has NO masks at all.
// Phase 2: per-node wave gather: 16 lanes/edge, idx via conflict-free LDS broadcast, 4 gathers
// in flight, packed f32x2 accumulate (v_pk_add_f32), shfl-xor reduce.

__global__ __launch_bounds__(256) void k_agg8(
    const unsigned char* __restrict__ feat8, const unsigned* __restrict__ recs,
    const int* __restrict__ bktcnt,
    const int* __restrict__ dstg, const int* __restrict__ srcg, int E,
    ushort* __restrict__ agg, int N)
{
    __shared__ unsigned lrec[CAP];
    __shared__ int ldeg[BWD], loffp[BWD + 1], lpos[BWD];

    const int b = (int)blockIdx.x;
    const int t = (int)threadIdx.x;
    const int wave = t >> 6, lane = t & 63;
    const int grp = lane >> 4, sub = lane & 15;   // 16 lanes/edge; lane covers cols [8*sub, 8*sub+8)
    const int cnt = bktcnt[b];
    const unsigned* brec = recs + (size_t)b * CAPB;

    if (t < BWD){ ldeg[t] = 0; lpos[t] = 0; }
    __syncthreads();

    auto writeout = [&](int node, int d, float a0, float a1, float a2, float a3,
                                          float a4, float a5, float a6, float a7){
        a0 += __shfl_xor(a0,16); a1 += __shfl_xor(a1,16); a2 += __shfl_xor(a2,16); a3 += __shfl_xor(a3,16);
        a4 += __shfl_xor(a4,16); a5 += __shfl_xor(a5,16); a6 += __shfl_xor(a6,16); a7 += __shfl_xor(a7,16);
        a0 += __shfl_xor(a0,32); a1 += __shfl_xor(a1,32); a2 += __shfl_xor(a2,32); a3 += __shfl_xor(a3,32);
        a4 += __shfl_xor(a4,32); a5 += __shfl_xor(a5,32); a6 += __shfl_xor(a6,32); a7 += __shfl_xor(a7,32);
        if (grp == 0){
            float inv = 1.f / (float)(d > 1 ? d : 1);
            uint4 r;
            r.x = (unsigned)f2bf(a0*inv) | ((unsigned)f2bf(a1*inv) << 16);
            r.y = (unsigned)f2bf(a2*inv) | ((unsigned)f2bf(a3*inv) << 16);
            r.z = (unsigned)f2bf(a4*inv) | ((unsigned)f2bf(a5*inv) << 16);
            r.w = (unsigned)f2bf(a6*inv) | ((unsigned)f2bf(a7*inv) << 16);
            *(uint4*)(agg + (size_t)node*FDIM + sub*8) = r;
        }
    };

    if (cnt <= CAPB){
        // ---- counting sort with per-node padding to x4 ----
        for (int i = t; i < cnt; i += 256) atomicAdd(&ldeg[(brec[i] >> 16) & (BWD-1)], 1);
        __syncthreads();
        if (t == 0){
            int r = 0;
            #pragma unroll
            for (int j = 0; j < BWD; j++){ loffp[j] = r; r += (ldeg[j] + 3) & ~3; }
            loffp[BWD] = r;               // <= cnt + 96 <= CAPB + 96 < CAP always
        }
        __syncthreads();
        for (int i = t; i < cnt; i += 256){
            const unsigned rec = brec[i];
            const int dl = (rec >> 16) & (BWD-1);
            lrec[loffp[dl] + atomicAdd(&lpos[dl], 1)] = rec;
        }
        if (t < BWD){                     // pad slots -> dummy row N (zeroed fp8)
            const int de = (ldeg[t] + 3) & ~3;
            for (int r = ldeg[t]; r < de; r++) lrec[loffp[t] + r] = (unsigned)N;
        }
        __syncthreads();

        // ---- per-node maskless gather ----
        for (int nl = wave; nl < BWD; nl += 4){
            const int node = b*BWD + nl;
            if (node >= N) break;
            const int o = loffp[nl], d = ldeg[nl];
            const int iters = ((d + 3) & ~3) >> 2;
            f32x2 a01{0.f,0.f}, a23{0.f,0.f}, a45{0.f,0.f}, a67{0.f,0.f};
            auto accum = [&](uint2 raw){
                a01 += __builtin_amdgcn_cvt_pk_f32_fp8((int)raw.x, false);
                a23 += __builtin_amdgcn_cvt_pk_f32_fp8((int)raw.x, true);
                a45 += __builtin_amdgcn_cvt_pk_f32_fp8((int)raw.y, false);
                a67 += __builtin_amdgcn_cvt_pk_f32_fp8((int)raw.y, true);
            };
            int j = 0;
            for (; j + 4 <= iters; j += 4){
                const int s0 = (int)(lrec[o + (j+0)*4 + grp] & 0xffffu);
                const int s1 = (int)(lrec[o + (j+1)*4 + grp] & 0xffffu);
                const int s2 = (int)(lrec[o + (j+2)*4 + grp] & 0xffffu);
                const int s3 = (int)(lrec[o + (j+3)*4 + grp] & 0xffffu);
                uint2 r0 = *(const uint2*)(feat8 + (size_t)s0*FDIM + sub*8);
                uint2 r1 = *(const uint2*)(feat8 + (size_t)s1*FDIM + sub*8);
                uint2 r2 = *(const uint2*)(feat8 + (size_t)s2*FDIM + sub*8);
                uint2 r3 = *(const uint2*)(feat8 + (size_t)s3*FDIM + sub*8);
                accum(r0); accum(r1); accum(r2); accum(r3);
            }
            for (; j < iters; j++){
                const int s = (int)(lrec[o + j*4 + grp] & 0xffffu);
                uint2 raw = *(const uint2*)(feat8 + (size_t)s*FDIM + sub*8);
                accum(raw);
            }
            writeout(node, d, a01.x,a01.y,a23.x,a23.y,a45.x,a45.y,a67.x,a67.y);
        }
    } else {
        // ---- fallback (bucket overflow; O(E) rescan of the raw edge list; never triggered here) ----
        for (int nl = wave; nl < BWD; nl += 4){
            const int node = b*BWD + nl;
            if (node >= N) break;
            f32x2 a01{0.f,0.f}, a23{0.f,0.f}, a45{0.f,0.f}, a67{0.f,0.f};
            int d = 0;
            for (int e = 0; e < E; e++){
                if (dstg[e] == node){
                    d++;
                    if (grp == 0){
                        uint2 raw = *(const uint2*)(feat8 + (size_t)srcg[e]*FDIM + sub*8);
                        a01 += __builtin_amdgcn_cvt_pk_f32_fp8((int)raw.x, false);
                        a23 += __builtin_amdgcn_cvt_pk_f32_fp8((int)raw.x, true);
                        a45 += __builtin_amdgcn_cvt_pk_f32_fp8((int)raw.y, false);
                        a67 += __builtin_amdgcn_cvt_pk_f32_fp8((int)raw.y, true);
                    }
                }
            }
            writeout(node, d, a01.x,a01.y,a23.x,a23.y,a45.x,a45.y,a67.x,a67.y);
        }
    }
}

// ---------------- LDS-weight linear (weights staged once/block, conflict-free ds_read_b128) ----------------
// Grid 512 x 4 waves; 2 row-tiles per wave. FP8OUT additionally emits fp8 copy of the output.

template<int NT, bool NORM, bool RELU, bool OUTF32, bool FP8OUT>
__global__ __launch_bounds__(256) void k_lin(
    const ushort* __restrict__ A1, const ushort* __restrict__ A2,
    const ushort* __restrict__ Wf, const float* __restrict__ bias,
    void* __restrict__ outv, unsigned char* __restrict__ out8, int N, int TILES)
{
    __shared__ __align__(16) ushort WS[NT*8*64*8];   // NT*8 KB
    {
        const uint4* wsrc = (const uint4*)Wf;
        uint4* wdst = (uint4*)WS;
        for (int i = threadIdx.x; i < NT*512; i += 256) wdst[i] = wsrc[i];
    }
    __syncthreads();

    const int wave = threadIdx.x >> 6, lane = threadIdx.x & 63;
    const int m = lane & 15, quad = lane >> 4;
    const ushort* WSl = WS + lane*8;    // frag (nt,kt) at WSl + (nt*8+kt)*512

    const int g  = blockIdx.x*4 + wave;          // 0..2047
    const int t0 = g, t1 = g + 2048;
    const bool has2 = (t1 < TILES);

    bf16x8 af0[8], af1[8];
    {
        int r0 = min(t0*16 + m, N-1);
        const ushort* p1 = A1 + (size_t)r0*FDIM + quad*8;
        const ushort* p2 = A2 + (size_t)r0*FDIM + quad*8;
        #pragma unroll
        for (int c = 0; c < 4; c++){
            af0[c]   = *(const bf16x8*)(p1 + c*32);
            af0[4+c] = *(const bf16x8*)(p2 + c*32);
        }
    }
    if (has2){
        int r1 = min(t1*16 + m, N-1);
        const ushort* p1 = A1 + (size_t)r1*FDIM + quad*8;
        const ushort* p2 = A2 + (size_t)r1*FDIM + quad*8;
        #pragma unroll
        for (int c = 0; c < 4; c++){
            af1[c]   = *(const bf16x8*)(p1 + c*32);
            af1[4+c] = *(const bf16x8*)(p2 + c*32);
        }
    }

    f32x4 acc0[NT], acc1[NT];
    #pragma unroll
    for (int nt = 0; nt < NT; nt++){ acc0[nt] = f32x4{0.f,0.f,0.f,0.f}; acc1[nt] = f32x4{0.f,0.f,0.f,0.f}; }

    if (has2){
        #pragma unroll
        for (int kt = 0; kt < 8; kt++)
            #pragma unroll
            for (int nt = 0; nt < NT; nt++){
                bf16x8 bfr = *(const bf16x8*)(WSl + (nt*8+kt)*512);
                acc0[nt] = __builtin_amdgcn_mfma_f32_16x16x32_bf16(af0[kt], bfr, acc0[nt], 0, 0, 0);
                acc1[nt] = __builtin_amdgcn_mfma_f32_16x16x32_bf16(af1[kt], bfr, acc1[nt], 0, 0, 0);
            }
    } else {
        #pragma unroll
        for (int kt = 0; kt < 8; kt++)
            #pragma unroll
            for (int nt = 0; nt < NT; nt++){
                bf16x8 bfr = *(const bf16x8*)(WSl + (nt*8+kt)*512);
                acc0[nt] = __builtin_amdgcn_mfma_f32_16x16x32_bf16(af0[kt], bfr, acc0[nt], 0, 0, 0);
            }
    }

    auto epi = [&](int t, f32x4* acc){
        #pragma unroll
        for (int nt = 0; nt < NT; nt++){
            float b = bias[nt*16 + m];
            acc[nt][0]+=b; acc[nt][1]+=b; acc[nt][2]+=b; acc[nt][3]+=b;
        }
        if (NORM){
            #pragma unroll
            for (int reg = 0; reg < 4; reg++){
                float ss = 0.f;
                #pragma unroll
                for (int nt = 0; nt < NT; nt++) ss += acc[nt][reg]*acc[nt][reg];
                ss += __shfl_xor(ss,1); ss += __shfl_xor(ss,2); ss += __shfl_xor(ss,4); ss += __shfl_xor(ss,8);
                float invn = 1.f / fmaxf(sqrtf(ss), 1e-12f);
                #pragma unroll
                for (int nt = 0; nt < NT; nt++) acc[nt][reg] *= invn;
            }
        }
        if (RELU){
            #pragma unroll
            for (int nt = 0; nt < NT; nt++){
                acc[nt][0]=fmaxf(acc[nt][0],0.f); acc[nt][1]=fmaxf(acc[nt][1],0.f);
                acc[nt][2]=fmaxf(acc[nt][2],0.f); acc[nt][3]=fmaxf(acc[nt][3],0.f);
            }
        }
        #pragma unroll
        for (int reg = 0; reg < 4; reg++){
            int row = t*16 + quad*4 + reg;
            if (row < N){
                if (OUTF32){
                    float* o = (float*)outv + (size_t)row*(NT*16) + m;
                    #pragma unroll
                    for (int nt = 0; nt < NT; nt++) o[nt*16] = acc[nt][reg];
                } else {
                    ushort* o = (ushort*)outv + (size_t)row*(NT*16) + m;
                    #pragma unroll
                    for (int nt = 0; nt < NT; nt++) o[nt*16] = f2bf(acc[nt][reg]);
                    if (FP8OUT){
                        unsigned char* o8 = out8 + (size_t)row*(NT*16) + m;
                        #pragma unroll
                        for (int nt = 0; nt < NT; nt++) o8[nt*16] = f2fp8(acc[nt][reg]);
                    }
                }
            }
        }
    };
    epi(t0, acc0);
    if (has2) epi(t1, acc1);
}

// ---------------- launch ----------------

extern "C" void kernel_launch(void* const* d_in, const int* in_sizes, int n_in,
                              void* d_out, int out_size, void* d_ws, size_t ws_size,
                              hipStream_t stream)
{
    const float* x    = (const float*)d_in[0];
    const int*   ei   = (const int*)  d_in[1];
    const float* W1_l = (const float*)d_in[2];
    const float* b1_l = (const float*)d_in[3];
    const float* W1_r = (const float*)d_in[4];
    const float* Wl1  = (const float*)d_in[5];
    const float* bl1  = (const float*)d_in[6];
    const float* W2_l = (const float*)d_in[7];
    const float* b2_l = (const float*)d_in[8];
    const float* W2_r = (const float*)d_in[9];
    float* out = (float*)d_out;

    const int N = in_sizes[0] / FDIM;   // 50000
    const int E = in_sizes[1] / 2;      // 800000

    const int* src = ei;
    const int* dst = ei + E;

    char* p = (char*)d_ws;
    auto carve = [&](size_t bytes) -> void* {
        void* r = (void*)p;
        p += (bytes + 255) & ~(size_t)255;
        return r;
    };

    const int SB  = 256;                         // scatter blocks (scanA scans over this dim)
    const int ESB = (E + SB - 1) / SB;           // 3125 edges per block
    const int NB  = (N + BWD - 1) >> BSH;        // 1563 buckets of 32 nodes

    int*           hist    = (int*)     carve((size_t)SB * NB * 4);
    int*           base    = (int*)     carve((size_t)SB * NB * 4);
    int*           bktcnt  = (int*)     carve((size_t)NB * 4);
    unsigned*      recs    = (unsigned*)carve((size_t)NB * CAPB * 4);
    ushort*        xb      = (ushort*)  carve((size_t)N * FDIM * 2);
    ushort*        h1b     = (ushort*)  carve((size_t)N * FDIM * 2);
    ushort*        hb      = (ushort*)  carve((size_t)N * FDIM * 2);
    ushort*        aggb    = (ushort*)  carve((size_t)N * FDIM * 2);
    unsigned char* x8      = (unsigned char*)carve((size_t)(N + 1) * FDIM);  // +1 dummy row
    unsigned char* h8      = (unsigned char*)carve((size_t)(N + 1) * FDIM);  // +1 dummy row
    ushort*        Wf1     = (ushort*)  carve((size_t)32768 * 2);
    ushort*        Wfm     = (ushort*)  carve((size_t)32768 * 2);
    ushort*        Wf2     = (ushort*)  carve((size_t)16384 * 2);

    const int gCast = (N * FDIM / 4 + 255) / 256;     // 6250
    const int gScan = (NB + SAB - 1) / SAB;           // 98
    const int TILES = (N + 15) / 16;                  // 3125
    const int gLin  = 512;                            // 2048 wave slots, 2 tiles/wave

    // pass 1: bucket histograms | x->bf16+fp8 | weight swizzle | dummy-row zero (fused)
    k_pass1<<<SB + gCast + 320 + 1, 256, 0, stream>>>(dst, hist, E, ESB, NB, SB,
                                                      x, xb, x8, h8, N*FDIM, gCast,
                                                      W1_l, W1_r, Wl1, W2_l, W2_r, Wf1, Wfm, Wf2);
    k_scanA<<<gScan, 256, 0, stream>>>(hist, base, bktcnt, NB);
    k_scatter<<<SB, 256, 0, stream>>>(dst, src, base, recs, E, ESB, NB);

    // layer 1: h1 = relu(norm([agg(x)|x] @ W1^T + b1))
    k_agg8<<<NB, 256, 0, stream>>>(x8, recs, bktcnt, dst, src, E, aggb, N);
    k_lin<8, true,  true,  false, false><<<gLin, 256, 0, stream>>>(aggb, xb, Wf1, b1_l, h1b, nullptr, N, TILES);

    // mid: h = relu([x|h1] @ Wl1^T + bl1)   (also emits fp8 copy for layer-2 gather)
    k_lin<8, false, true,  false, true ><<<gLin, 256, 0, stream>>>(xb, h1b, Wfm, bl1, hb, h8, N, TILES);

    // layer 2: out = norm([agg(h)|h] @ W2^T + b2)  (fp32 out)
    k_agg8<<<NB, 256, 0, stream>>>(h8, recs, bktcnt, dst, src, E, aggb, N);
    k_lin<4, true,  false, true,  false><<<gLin, 256, 0, stream>>>(aggb, hb, Wf2, b2_l, out, nullptr, N, TILES);
}